// Round 4
// baseline (527.557 us; speedup 1.0000x reference)
//
#include <hip/hip_runtime.h>
#include <hip/hip_bf16.h>

typedef _Float16 f16;
typedef _Float16 f16x8 __attribute__((ext_vector_type(8)));
typedef _Float16 f16x4 __attribute__((ext_vector_type(4)));
typedef float f32x4 __attribute__((ext_vector_type(4)));

#define NBATCH 32
#define WH     1024
#define LSEQ   512
#define DIM    768
#define BK     32   // attn_s K-step

#define GLD16(gp, lp) __builtin_amdgcn_global_load_lds( \
    (const __attribute__((address_space(1))) void*)(gp), \
    (__attribute__((address_space(3))) void*)(lp), 16, 0, 0)

#define SB()    { __builtin_amdgcn_sched_barrier(0); __builtin_amdgcn_s_barrier(); __builtin_amdgcn_sched_barrier(0); }
#define LGKM0() { asm volatile("s_waitcnt lgkmcnt(0)" ::: "memory"); __builtin_amdgcn_sched_barrier(0); }
#define VM4()   { asm volatile("s_waitcnt vmcnt(4)" ::: "memory"); __builtin_amdgcn_sched_barrier(0); }
#define P1()    __builtin_amdgcn_s_setprio(1)
#define P0()    __builtin_amdgcn_s_setprio(0)

// ---------------- casts ----------------
__global__ void cast8(const float* __restrict__ src, f16* __restrict__ dst, int n8) {
    int i = blockIdx.x * blockDim.x + threadIdx.x;
    if (i < n8) {
        float4 a = ((const float4*)src)[i * 2];
        float4 b = ((const float4*)src)[i * 2 + 1];
        f16x8 h = { (f16)a.x,(f16)a.y,(f16)a.z,(f16)a.w,
                    (f16)b.x,(f16)b.y,(f16)b.z,(f16)b.w };
        ((f16x8*)dst)[i] = h;
    }
}

// ---------------- 256x256 8-phase GEMM (T3+T4+T5+T2) ----------------
// C[M,N] = (A[M,K] * B[N,K]^T + bias) * scale, A/B f16 K-major.
// 8 waves (2M x 4N), BK=64, LDS 128KB: As/Bs[2 dbuf][2 half][128][64],
// XOR-swizzle slot^(row&7). Counted vmcnt(4) at ph3/ph7 only.
// OUT_MODE: 0 = f16 [R][768]; 1 = f16 transposed VpT[b][768][512]; 2 = f32 [z][R][768]
#define RD_A(d, qm, kk, af) { _Pragma("unroll") \
    for (int mf = 0; mf < 4; ++mf) { int lr = (qm)*64 + mf*16 + lo; \
        af[mf] = *(const f16x8*)&As[d][wm][lr][(((kk)*4 + hi) ^ (lr & 7)) << 3]; } }
#define RD_B(d, kk, bf) { _Pragma("unroll") \
    for (int nf = 0; nf < 4; ++nf) { int lr = bnb + nf*16 + lo; \
        bf[nf] = *(const f16x8*)&Bs[d][hb][lr][(((kk)*4 + hi) ^ (lr & 7)) << 3]; } }
#define MM(qm, af, bf) { _Pragma("unroll") \
    for (int mf = 0; mf < 4; ++mf) { _Pragma("unroll") \
        for (int nf = 0; nf < 4; ++nf) \
            acc[(qm)*4 + mf][nf] = __builtin_amdgcn_mfma_f32_16x16x32_f16(af[mf], bf[nf], acc[(qm)*4 + mf][nf], 0, 0, 0); } }

template<int OUT_MODE, bool HAS_BIAS>
__global__ __launch_bounds__(512, 2) void gemm8(
    const f16* __restrict__ Ap, const f16* __restrict__ Bp,
    const float* __restrict__ bias, float scale, void* __restrict__ Cp,
    int Mtiles, int Ntiles, int K, long sA, long sB, long sC)
{
    __shared__ __align__(16) f16 As[2][2][128][64];
    __shared__ __align__(16) f16 Bs[2][2][128][64];

    const int nwg = gridDim.x;
    const int bid = blockIdx.x;
    const int swz = (bid & 7) * (nwg >> 3) + (bid >> 3);   // bijective: nwg % 8 == 0
    const int per_z = Mtiles * Ntiles;
    const int z   = swz / per_z;
    const int rem = swz - z * per_z;
    const int mt = rem / Ntiles, nt = rem % Ntiles;

    const f16* Ab = Ap + (long)z * sA + (long)mt * 256 * K;
    const f16* Bb = Bp + (long)z * sB + (long)nt * 256 * K;

    const int tid = threadIdx.x;
    const int w = tid >> 6, lane = tid & 63;
    const int lo = lane & 15, hi = lane >> 4;
    const int wm = w >> 2, wn = w & 3;
    const int hb = wn >> 1;
    const int bnb = (wn & 1) * 64;

    const int NKT = K >> 6;      // 64-wide K-tiles (even: 12 or 8)
    const int NI  = NKT >> 1;

    f32x4 acc[8][4] = {};

    // staging geometry: per instr, 512 thr x 16B = 64 rows; lane covers row w*8+(lane>>3)
    const int srow = lane >> 3;          // 0..7 within wave's 8-row chunk
    const int sslot = lane & 7;

    auto stageA = [&](int kt, int half) {
        int ktc = kt < NKT ? kt : kt - 2;
        int d = kt & 1;
        #pragma unroll
        for (int j = 0; j < 2; ++j) {
            int lr = j * 64 + w * 8 + srow;
            const f16* gp = Ab + (long)(half * 128 + lr) * K + ktc * 64 + ((sslot ^ (lr & 7)) << 3);
            GLD16(gp, &As[d][half][j * 64 + w * 8][0]);
        }
    };
    auto stageB = [&](int kt, int half) {
        int ktc = kt < NKT ? kt : kt - 2;
        int d = kt & 1;
        #pragma unroll
        for (int j = 0; j < 2; ++j) {
            int lr = j * 64 + w * 8 + srow;
            const f16* gp = Bb + (long)(half * 128 + lr) * K + ktc * 64 + ((sslot ^ (lr & 7)) << 3);
            GLD16(gp, &Bs[d][half][j * 64 + w * 8][0]);
        }
    };

    // prologue: kt0-B, kt0-A, kt1-B staged; wait oldest 8 (all kt0); kt1-B stays in flight
    stageB(0, 0); stageB(0, 1);
    stageA(0, 0); stageA(0, 1);
    stageB(1, 0); stageB(1, 1);
    VM4(); SB();

    for (int it = 0; it < NI; ++it) {
        const int kt = it * 2;
        f16x8 af[4], bf0[4], bf1[4];
        // ---- K-tile kt (dbuf 0) ----
        RD_A(0, 0, 0, af); RD_B(0, 0, bf0);
        stageA(kt + 1, 0);
        SB(); LGKM0(); P1(); MM(0, af, bf0); P0(); SB();

        RD_A(0, 0, 1, af); RD_B(0, 1, bf1);
        stageA(kt + 1, 1);
        SB(); LGKM0(); P1(); MM(0, af, bf1); P0(); SB();

        RD_A(0, 1, 0, af);
        stageB(kt + 2, 0);
        SB(); LGKM0(); P1(); MM(1, af, bf0); P0(); SB();

        RD_A(0, 1, 1, af);
        stageB(kt + 2, 1);
        SB(); LGKM0(); P1(); MM(1, af, bf1); P0(); VM4(); SB();

        // ---- K-tile kt+1 (dbuf 1) ----
        RD_A(1, 0, 0, af); RD_B(1, 0, bf0);
        stageA(kt + 2, 0);
        SB(); LGKM0(); P1(); MM(0, af, bf0); P0(); SB();

        RD_A(1, 0, 1, af); RD_B(1, 1, bf1);
        stageA(kt + 2, 1);
        SB(); LGKM0(); P1(); MM(0, af, bf1); P0(); SB();

        RD_A(1, 1, 0, af);
        stageB(kt + 3, 0);
        SB(); LGKM0(); P1(); MM(1, af, bf0); P0(); SB();

        RD_A(1, 1, 1, af);
        stageB(kt + 3, 1);
        SB(); LGKM0(); P1(); MM(1, af, bf1); P0(); VM4(); SB();
    }

    // ---- epilogue ----
    #pragma unroll
    for (int nf = 0; nf < 4; ++nf) {
        int col = nt * 256 + wn * 64 + nf * 16 + lo;
        float bv = HAS_BIAS ? bias[col] : 0.0f;
        #pragma unroll
        for (int mf = 0; mf < 8; ++mf) {
            long R = (long)mt * 256 + wm * 128 + mf * 16 + hi * 4;
            if constexpr (OUT_MODE == 1) {
                long b2 = R >> 9, l = R & 511;
                f16x4 o;
                #pragma unroll
                for (int r = 0; r < 4; ++r) o[r] = (f16)((acc[mf][nf][r] + bv) * scale);
                *(f16x4*)((f16*)Cp + b2 * (768L * 512) + (long)col * 512 + l) = o;
            } else if constexpr (OUT_MODE == 0) {
                #pragma unroll
                for (int r = 0; r < 4; ++r)
                    ((f16*)Cp)[(R + r) * 768 + col] = (f16)((acc[mf][nf][r] + bv) * scale);
            } else {
                #pragma unroll
                for (int r = 0; r < 4; ++r)
                    ((float*)Cp)[(long)z * sC + (R + r) * 768 + col] = (acc[mf][nf][r] + bv) * scale;
            }
        }
    }
}

// ---------------- S = Qp*Kp^T, softmax, P f16 (unchanged, verified) ----------------
__global__ __launch_bounds__(256, 2) void attn_s(
    const f16* __restrict__ Qp, const f16* __restrict__ Kp, f16* __restrict__ P)
{
    __shared__ __align__(16) f16 Ks[2][512][32];
    __shared__ __align__(16) f16 Qs[2][64][32];

    int bid = blockIdx.x;
    int swz = (bid & 7) * 64 + (bid >> 3);
    int batch = swz >> 4;
    int qblk  = swz & 15;

    const int tid = threadIdx.x;
    const int lane = tid & 63, w = tid >> 6;
    const int lo = lane & 15, hi = lane >> 4;
    const int cr = lane >> 2, cs = lane & 3;

    const f16* Qb = Qp + (long)batch * WH * DIM + (long)qblk * 64 * DIM;
    const f16* Kb = Kp + (long)batch * LSEQ * DIM;

    f32x4 acc[32] = {};

    auto stage = [&](int t, int buf) {
        int k0 = t * BK;
        #pragma unroll
        for (int i = 0; i < 8; ++i) {
            int ch = w * 8 + i;
            int r  = ch * 16 + cr;
            const f16* gp = Kb + (long)r * DIM + k0 + ((cs ^ ((r >> 1) & 3)) << 3);
            GLD16(gp, &Ks[buf][ch * 16][0]);
        }
        {
            int r = w * 16 + cr;
            const f16* gp = Qb + (long)r * DIM + k0 + ((cs ^ ((r >> 1) & 3)) << 3);
            GLD16(gp, &Qs[buf][w * 16][0]);
        }
    };

    stage(0, 0);
    int c = 0;
    const int NT = DIM / BK;
    for (int t = 0; t < NT; ++t) {
        __syncthreads();
        if (t + 1 < NT) stage(t + 1, c ^ 1);
        int rQ = w * 16 + lo;
        f16x8 qf = *(const f16x8*)&Qs[c][rQ][(hi ^ ((rQ >> 1) & 3)) << 3];
        #pragma unroll
        for (int lt = 0; lt < 32; ++lt) {
            int rK = lt * 16 + lo;
            f16x8 kf = *(const f16x8*)&Ks[c][rK][(hi ^ ((rK >> 1) & 3)) << 3];
            acc[lt] = __builtin_amdgcn_mfma_f32_16x16x32_f16(kf, qf, acc[lt], 0, 0, 0);
        }
        c ^= 1;
    }

    float mx = -1e30f;
    #pragma unroll
    for (int lt = 0; lt < 32; ++lt)
        #pragma unroll
        for (int r = 0; r < 4; ++r) mx = fmaxf(mx, acc[lt][r]);
    mx = fmaxf(mx, __shfl_xor(mx, 16));
    mx = fmaxf(mx, __shfl_xor(mx, 32));

    float sum = 0.f;
    #pragma unroll
    for (int lt = 0; lt < 32; ++lt) {
        #pragma unroll
        for (int r = 0; r < 4; ++r) {
            float p = exp2f((acc[lt][r] - mx) * 1.44269504088896f);
            acc[lt][r] = p;
            sum += p;
        }
    }
    sum += __shfl_xor(sum, 16);
    sum += __shfl_xor(sum, 32);
    float inv = 1.0f / sum;

    f16* Prow = P + (long)batch * WH * LSEQ + (long)(qblk * 64 + w * 16 + lo) * LSEQ;
    #pragma unroll
    for (int lt = 0; lt < 32; ++lt) {
        f16x4 o;
        #pragma unroll
        for (int r = 0; r < 4; ++r) o[r] = (f16)(acc[lt][r] * inv);
        *(f16x4*)(Prow + lt * 16 + hi * 4) = o;
    }
}

extern "C" void kernel_launch(void* const* d_in, const int* in_sizes, int n_in,
                              void* d_out, int out_size, void* d_ws, size_t ws_size,
                              hipStream_t stream) {
    const float* q   = (const float*)d_in[0];
    const float* k   = (const float*)d_in[1];
    const float* v   = (const float*)d_in[2];
    const float* q_w = (const float*)d_in[3];
    const float* q_b = (const float*)d_in[4];
    const float* k_w = (const float*)d_in[5];
    const float* k_b = (const float*)d_in[6];
    const float* v_w = (const float*)d_in[7];
    const float* v_b = (const float*)d_in[8];
    float* out = (float*)d_out;

    const long NW   = 768L * 768;
    const long NQ   = (long)NBATCH * WH * DIM;    // 25165824
    const long NKV  = (long)NBATCH * LSEQ * DIM;  // 12582912

    // d_ws: weights + intermediates (same 137.8MB footprint as round 2)
    f16* qw16 = (f16*)d_ws;
    f16* kw16 = qw16 + NW;
    f16* vw16 = kw16 + NW;
    f16* Qp   = vw16 + NW;
    f16* Kp   = Qp + NQ;
    f16* VpT  = Kp + NKV;
    f16* P    = VpT + NKV;

    // d_out doubles as scratch for f16 input casts (exactly 100663296 B);
    // dead before PV writes the real output.
    f16* q16 = (f16*)d_out;
    f16* k16 = q16 + NQ;
    f16* v16 = k16 + NKV;

    cast8<<<(int)(NW / 8 / 256), 256, 0, stream>>>(q_w, qw16, (int)(NW / 8));
    cast8<<<(int)(NW / 8 / 256), 256, 0, stream>>>(k_w, kw16, (int)(NW / 8));
    cast8<<<(int)(NW / 8 / 256), 256, 0, stream>>>(v_w, vw16, (int)(NW / 8));
    cast8<<<(int)(NQ / 8 / 256), 256, 0, stream>>>(q, q16, (int)(NQ / 8));
    cast8<<<(int)(NKV / 8 / 256), 256, 0, stream>>>(k, k16, (int)(NKV / 8));
    cast8<<<(int)(NKV / 8 / 256), 256, 0, stream>>>(v, v16, (int)(NKV / 8));

    const float qscale = 0.03608439182435161f;  // 1/sqrt(768)

    // Qp = (q16 * qw^T + q_b) * scale     flat [32768,768] f16
    gemm8<0, true><<<384, 512, 0, stream>>>(q16, qw16, q_b, qscale, Qp,
                                            128, 3, DIM, 0, 0, 0);
    // Kp = k16 * kw^T + k_b               flat [16384,768] f16
    gemm8<0, true><<<192, 512, 0, stream>>>(k16, kw16, k_b, 1.0f, Kp,
                                            64, 3, DIM, 0, 0, 0);
    // VpT = (v16 * vw^T + v_b)^T          [32][768][512] f16
    gemm8<1, true><<<192, 512, 0, stream>>>(v16, vw16, v_b, 1.0f, VpT,
                                            64, 3, DIM, 0, 0, 0);
    // P = softmax(Qp * Kp^T)              [32,1024,512] f16
    attn_s<<<512, 256, 0, stream>>>(Qp, Kp, P);
    // out = P * Vp                        [32,1024,768] f32
    gemm8<2, false><<<384, 512, 0, stream>>>(P, VpT, nullptr, 1.0f, out,
                                             4, 3, LSEQ,
                                             (long)WH * LSEQ, (long)DIM * LSEQ, (long)WH * DIM);
}

// Round 6
// 508.459 us; speedup vs baseline: 1.0376x; 1.0376x over previous
//
#include <hip/hip_runtime.h>
#include <hip/hip_bf16.h>

typedef _Float16 f16;
typedef _Float16 f16x8 __attribute__((ext_vector_type(8)));
typedef _Float16 f16x4 __attribute__((ext_vector_type(4)));
typedef float f32x4 __attribute__((ext_vector_type(4)));

#define NBATCH 32
#define WH     1024
#define LSEQ   512
#define DIM    768

#define GLD16(gp, lp) __builtin_amdgcn_global_load_lds( \
    (const __attribute__((address_space(1))) void*)(gp), \
    (__attribute__((address_space(3))) void*)(lp), 16, 0, 0)

#define SB()    { __builtin_amdgcn_sched_barrier(0); __builtin_amdgcn_s_barrier(); __builtin_amdgcn_sched_barrier(0); }
#define LGKM0() { asm volatile("s_waitcnt lgkmcnt(0)" ::: "memory"); __builtin_amdgcn_sched_barrier(0); }
#define VM4()   { asm volatile("s_waitcnt vmcnt(4)" ::: "memory"); __builtin_amdgcn_sched_barrier(0); }
#define VM0()   { asm volatile("s_waitcnt vmcnt(0)" ::: "memory"); __builtin_amdgcn_sched_barrier(0); }
#define P1()    __builtin_amdgcn_s_setprio(1)
#define P0()    __builtin_amdgcn_s_setprio(0)

// ---------------- merged cast: 3 weights + q,k,v -> f16, one dispatch ----------------
__global__ void cast_all(
    const float* __restrict__ qw, const float* __restrict__ kw, const float* __restrict__ vw,
    const float* __restrict__ q,  const float* __restrict__ k,  const float* __restrict__ v,
    f16* __restrict__ dqw, f16* __restrict__ dkw, f16* __restrict__ dvw,
    f16* __restrict__ dq,  f16* __restrict__ dk,  f16* __restrict__ dv)
{
    long i = (long)blockIdx.x * blockDim.x + threadIdx.x;   // f16x8 unit index
    const float* src; f16* dst; long o;
    if      (i < 73728L)   { src = qw; dst = dqw; o = i; }
    else if (i < 147456L)  { src = kw; dst = dkw; o = i - 73728L; }
    else if (i < 221184L)  { src = vw; dst = dvw; o = i - 147456L; }
    else if (i < 3366912L) { src = q;  dst = dq;  o = i - 221184L; }
    else if (i < 4939776L) { src = k;  dst = dk;  o = i - 3366912L; }
    else                   { src = v;  dst = dv;  o = i - 4939776L; }
    float4 a = ((const float4*)src)[o * 2];
    float4 b = ((const float4*)src)[o * 2 + 1];
    f16x8 h = { (f16)a.x,(f16)a.y,(f16)a.z,(f16)a.w,
                (f16)b.x,(f16)b.y,(f16)b.z,(f16)b.w };
    ((f16x8*)dst)[o] = h;
}

// ---------------- merged 256x256 8-phase projection GEMM ----------------
// One dispatch does Qp, Kp, VpT. Region by block id:
//   swz <384: Qp = (q16*qw^T+q_b)*scale ; <576: Kp ; else VpT (transposed out).
#define RD_A(d, qm, kk, af) { _Pragma("unroll") \
    for (int mf = 0; mf < 4; ++mf) { int lr = (qm)*64 + mf*16 + lo; \
        af[mf] = *(const f16x8*)&As[d][wm][lr][(((kk)*4 + hi) ^ (lr & 7)) << 3]; } }
#define RD_B(d, kk, bf) { _Pragma("unroll") \
    for (int nf = 0; nf < 4; ++nf) { int lr = bnb + nf*16 + lo; \
        bf[nf] = *(const f16x8*)&Bs[d][hb][lr][(((kk)*4 + hi) ^ (lr & 7)) << 3]; } }
#define MM(qm, af, bf) { _Pragma("unroll") \
    for (int mf = 0; mf < 4; ++mf) { _Pragma("unroll") \
        for (int nf = 0; nf < 4; ++nf) \
            acc[(qm)*4 + mf][nf] = __builtin_amdgcn_mfma_f32_16x16x32_f16(af[mf], bf[nf], acc[(qm)*4 + mf][nf], 0, 0, 0); } }

__global__ __launch_bounds__(512, 2) void proj_all(
    const f16* __restrict__ in16,
    const f16* __restrict__ qw, const f16* __restrict__ kw, const f16* __restrict__ vw,
    const float* __restrict__ q_b, const float* __restrict__ k_b, const float* __restrict__ v_b,
    f16* __restrict__ Qp, f16* __restrict__ Kp, f16* __restrict__ VpT, float qscale)
{
    __shared__ __align__(16) f16 As[2][2][128][64];
    __shared__ __align__(16) f16 Bs[2][2][128][64];

    const int bid = blockIdx.x;
    const int swz = (bid & 7) * 96 + (bid >> 3);   // 768 % 8 == 0, bijective

    int rgn, g;
    const f16 *Abase, *Bw; const float* bias; float scale;
    if (swz < 384)      { rgn = 0; g = swz;       Abase = in16;                           Bw = qw; bias = q_b; scale = qscale; }
    else if (swz < 576) { rgn = 1; g = swz - 384; Abase = in16 + 25165824L;               Bw = kw; bias = k_b; scale = 1.0f; }
    else                { rgn = 2; g = swz - 576; Abase = in16 + 25165824L + 12582912L;   Bw = vw; bias = v_b; scale = 1.0f; }
    const int mt = g / 3, nt = g % 3;
    const f16* Ab = Abase + (long)mt * 256 * DIM;
    const f16* Bb = Bw + (long)nt * 256 * DIM;

    const int tid = threadIdx.x;
    const int w = tid >> 6, lane = tid & 63;
    const int lo = lane & 15, hi = lane >> 4;
    const int wm = w >> 2, wn = w & 3;
    const int hb = wn >> 1;
    const int bnb = (wn & 1) * 64;

    const int NKT = 12;   // 768/64
    const int NI  = 6;

    f32x4 acc[8][4] = {};

    const int srow = lane >> 3, sslot = lane & 7;

    auto stageA = [&](int kt, int half) {
        int ktc = kt < NKT ? kt : kt - 2;
        int d = kt & 1;
        #pragma unroll
        for (int j = 0; j < 2; ++j) {
            int lr = j * 64 + w * 8 + srow;
            const f16* gp = Ab + (long)(half * 128 + lr) * DIM + ktc * 64 + ((sslot ^ (lr & 7)) << 3);
            GLD16(gp, &As[d][half][j * 64 + w * 8][0]);
        }
    };
    auto stageB = [&](int kt, int half) {
        int ktc = kt < NKT ? kt : kt - 2;
        int d = kt & 1;
        #pragma unroll
        for (int j = 0; j < 2; ++j) {
            int lr = j * 64 + w * 8 + srow;
            const f16* gp = Bb + (long)(half * 128 + lr) * DIM + ktc * 64 + ((sslot ^ (lr & 7)) << 3);
            GLD16(gp, &Bs[d][half][j * 64 + w * 8][0]);
        }
    };

    stageB(0, 0); stageB(0, 1);
    stageA(0, 0); stageA(0, 1);
    stageB(1, 0); stageB(1, 1);
    VM4(); SB();

    for (int it = 0; it < NI; ++it) {
        const int kt = it * 2;
        f16x8 af[4], bf0[4], bf1[4];
        RD_A(0, 0, 0, af); RD_B(0, 0, bf0);
        stageA(kt + 1, 0);
        SB(); LGKM0(); P1(); MM(0, af, bf0); P0(); SB();

        RD_A(0, 0, 1, af); RD_B(0, 1, bf1);
        stageA(kt + 1, 1);
        SB(); LGKM0(); P1(); MM(0, af, bf1); P0(); SB();

        RD_A(0, 1, 0, af);
        stageB(kt + 2, 0);
        SB(); LGKM0(); P1(); MM(1, af, bf0); P0(); SB();

        RD_A(0, 1, 1, af);
        stageB(kt + 2, 1);
        SB(); LGKM0(); P1(); MM(1, af, bf1); P0(); VM4(); SB();

        RD_A(1, 0, 0, af); RD_B(1, 0, bf0);
        stageA(kt + 2, 0);
        SB(); LGKM0(); P1(); MM(0, af, bf0); P0(); SB();

        RD_A(1, 0, 1, af); RD_B(1, 1, bf1);
        stageA(kt + 2, 1);
        SB(); LGKM0(); P1(); MM(0, af, bf1); P0(); SB();

        RD_A(1, 1, 0, af);
        stageB(kt + 3, 0);
        SB(); LGKM0(); P1(); MM(1, af, bf0); P0(); SB();

        RD_A(1, 1, 1, af);
        stageB(kt + 3, 1);
        SB(); LGKM0(); P1(); MM(1, af, bf1); P0(); VM4(); SB();
    }

    // epilogue (runtime region switch; branches are block-uniform)
    #pragma unroll
    for (int nf = 0; nf < 4; ++nf) {
        int col = nt * 256 + wn * 64 + nf * 16 + lo;
        float bv = bias[col];
        #pragma unroll
        for (int mf = 0; mf < 8; ++mf) {
            long R = (long)mt * 256 + wm * 128 + mf * 16 + hi * 4;
            if (rgn == 2) {
                long b2 = R >> 9, l = R & 511;
                f16x4 o;
                #pragma unroll
                for (int r = 0; r < 4; ++r) o[r] = (f16)((acc[mf][nf][r] + bv) * scale);
                *(f16x4*)(VpT + b2 * (768L * 512) + (long)col * 512 + l) = o;
            } else {
                f16* dst = (rgn == 0) ? Qp : Kp;
                #pragma unroll
                for (int r = 0; r < 4; ++r)
                    dst[(R + r) * 768 + col] = (f16)((acc[mf][nf][r] + bv) * scale);
            }
        }
    }
    VM0();  // drain dummy tail stages before endpgm
}

// ---------------- fused attention: S = Qp*Kp^T, softmax, out = P*Vp ----------------
// Block = 64 q-rows of one batch, 4 waves, 96KB LDS.
// Phase 1 (QK+softmax): identical structure to the verified attn_s.
// Phase 2: P (normalized f16) -> LDS (64x512, XOR-swizzled 16B slots).
// Phase 3: PV: 3 d-passes of 256; V tiles [256 d][32 l] dbuf via gld_lds, vmcnt(4).
__global__ __launch_bounds__(256, 1) void attn_fused(
    const f16* __restrict__ Qp, const f16* __restrict__ Kp,
    const f16* __restrict__ VpT, float* __restrict__ out)
{
    __shared__ __align__(16) char smem[98304];
    f16* KsB = (f16*)smem;              // phase1: [2][512][32]
    f16* QsB = (f16*)(smem + 65536);    // phase1: [2][64][32]
    f16* Pl  = (f16*)smem;              // phase3: [64][512] swizzled
    f16* Vs  = (f16*)(smem + 65536);    // phase3: [2][256][32]

    const int bid = blockIdx.x;
    const int swz = (bid & 7) * 64 + (bid >> 3);   // 512 % 8 == 0
    const int batch = swz >> 4, qblk = swz & 15;

    const int tid = threadIdx.x;
    const int lane = tid & 63, w = tid >> 6;
    const int lo = lane & 15, hi = lane >> 4;
    const int cr = lane >> 2, cs = lane & 3;

    const f16* Qb = Qp + (long)batch * WH * DIM + (long)qblk * 64 * DIM;
    const f16* Kb = Kp + (long)batch * LSEQ * DIM;
    const f16* Vb = VpT + (long)batch * 768L * 512;

    f32x4 acc[32] = {};

    auto stage = [&](int t, int buf) {
        int k0 = t * 32;
        #pragma unroll
        for (int i = 0; i < 8; ++i) {
            int ch = w * 8 + i;
            int r  = ch * 16 + cr;
            const f16* gp = Kb + (long)r * DIM + k0 + ((cs ^ ((r >> 1) & 3)) << 3);
            GLD16(gp, KsB + ((long)buf * 512 + ch * 16) * 32);
        }
        {
            int r = w * 16 + cr;
            const f16* gp = Qb + (long)r * DIM + k0 + ((cs ^ ((r >> 1) & 3)) << 3);
            GLD16(gp, QsB + ((long)buf * 64 + w * 16) * 32);
        }
    };

    // ---- phase 1: QK^T (swapped operands) ----
    stage(0, 0);
    int c = 0;
    const int NT = DIM / 32;   // 24
    for (int t = 0; t < NT; ++t) {
        __syncthreads();
        if (t + 1 < NT) stage(t + 1, c ^ 1);
        int rQ = w * 16 + lo;
        f16x8 qf = *(const f16x8*)&QsB[((long)c * 64 + rQ) * 32 + ((hi ^ ((rQ >> 1) & 3)) << 3)];
        #pragma unroll
        for (int lt = 0; lt < 32; ++lt) {
            int rK = lt * 16 + lo;
            f16x8 kf = *(const f16x8*)&KsB[((long)c * 512 + rK) * 32 + ((hi ^ ((rK >> 1) & 3)) << 3)];
            acc[lt] = __builtin_amdgcn_mfma_f32_16x16x32_f16(kf, qf, acc[lt], 0, 0, 0);
        }
        c ^= 1;
    }

    // ---- softmax (in-register; lane holds S[l slice][q=lo]) ----
    float mx = -1e30f;
    #pragma unroll
    for (int lt = 0; lt < 32; ++lt)
        #pragma unroll
        for (int r = 0; r < 4; ++r) mx = fmaxf(mx, acc[lt][r]);
    mx = fmaxf(mx, __shfl_xor(mx, 16));
    mx = fmaxf(mx, __shfl_xor(mx, 32));
    float sum = 0.f;
    #pragma unroll
    for (int lt = 0; lt < 32; ++lt)
        #pragma unroll
        for (int r = 0; r < 4; ++r) {
            float p = exp2f((acc[lt][r] - mx) * 1.44269504088896f);
            acc[lt][r] = p;
            sum += p;
        }
    sum += __shfl_xor(sum, 16);
    sum += __shfl_xor(sum, 32);
    float inv = 1.0f / sum;

    // ---- phase 2: P -> LDS ----
    auto stageV = [&](int s, int buf) {
        int dt = s >> 4, ls = s & 15;
        #pragma unroll
        for (int c2 = 0; c2 < 4; ++c2) {
            int dr = c2 * 64 + w * 16 + (lane >> 2);
            int slot = lane & 3;
            const f16* gp = Vb + (long)(dt * 256 + dr) * 512 + ls * 32 + ((slot ^ (dr & 3)) << 3);
            GLD16(gp, Vs + ((long)(buf * 256 + c2 * 64 + w * 16)) * 32);
        }
    };

    __syncthreads();            // all waves done reading Ks/Qs
    stageV(0, 0);               // prefetch first V tile into freed Qs region
    {
        int q = w * 16 + lo;    // local q-row
        #pragma unroll
        for (int lt = 0; lt < 32; ++lt) {
            f16x4 o;
            #pragma unroll
            for (int r = 0; r < 4; ++r) o[r] = (f16)(acc[lt][r] * inv);
            int slot = (lt * 2 + (hi >> 1)) ^ (q & 7);
            *(f16x4*)(Pl + (long)q * 512 + slot * 8 + ((hi & 1) << 2)) = o;
        }
    }
    LGKM0(); SB();

    // ---- phase 3: PV ----
    int b = 0;
    for (int dt = 0; dt < 3; ++dt) {
        f32x4 pacc[4][4] = {};   // [m][nf]: rows q = m*16.., cols d = dt*256 + w*64 + nf*16..
        for (int ls2 = 0; ls2 < 16; ++ls2) {
            int s = dt * 16 + ls2;
            stageV(s + 1 < 48 ? s + 1 : 46, b ^ 1);
            VM4(); SB();
            f16x8 pa[4], vbf[4];
            #pragma unroll
            for (int m = 0; m < 4; ++m) {
                int q2 = m * 16 + lo;
                pa[m] = *(const f16x8*)&Pl[(long)q2 * 512 + (((ls2 * 4 + hi) ^ (q2 & 7)) << 3)];
            }
            #pragma unroll
            for (int nf = 0; nf < 4; ++nf) {
                int dr = w * 64 + nf * 16 + lo;
                vbf[nf] = *(const f16x8*)&Vs[((long)(b * 256 + dr)) * 32 + ((hi ^ (dr & 3)) << 3)];
            }
            #pragma unroll
            for (int m = 0; m < 4; ++m)
                #pragma unroll
                for (int nf = 0; nf < 4; ++nf)
                    pacc[m][nf] = __builtin_amdgcn_mfma_f32_16x16x32_f16(pa[m], vbf[nf], pacc[m][nf], 0, 0, 0);
            SB();
            b ^= 1;
        }
        float* ob = out + ((long)batch * WH + (long)qblk * 64) * 768 + dt * 256 + w * 64;
        #pragma unroll
        for (int nf = 0; nf < 4; ++nf)
            #pragma unroll
            for (int m = 0; m < 4; ++m)
                #pragma unroll
                for (int r = 0; r < 4; ++r)
                    ob[(long)(m * 16 + hi * 4 + r) * 768 + nf * 16 + lo] = pacc[m][nf][r];
    }
    VM0();  // drain dummy tail stages before endpgm
}

extern "C" void kernel_launch(void* const* d_in, const int* in_sizes, int n_in,
                              void* d_out, int out_size, void* d_ws, size_t ws_size,
                              hipStream_t stream) {
    const float* q   = (const float*)d_in[0];
    const float* k   = (const float*)d_in[1];
    const float* v   = (const float*)d_in[2];
    const float* q_w = (const float*)d_in[3];
    const float* q_b = (const float*)d_in[4];
    const float* k_w = (const float*)d_in[5];
    const float* k_b = (const float*)d_in[6];
    const float* v_w = (const float*)d_in[7];
    const float* v_b = (const float*)d_in[8];
    float* out = (float*)d_out;

    const long NW  = 768L * 768;
    const long NQ  = (long)NBATCH * WH * DIM;    // 25165824
    const long NKV = (long)NBATCH * LSEQ * DIM;  // 12582912

    f16* qw16 = (f16*)d_ws;
    f16* kw16 = qw16 + NW;
    f16* vw16 = kw16 + NW;
    f16* Qp   = vw16 + NW;
    f16* Kp   = Qp + NQ;
    f16* VpT  = Kp + NKV;     // ~104 MB total in d_ws

    // d_out as scratch for f16 input casts (exactly out_size bytes); dead before attn writes out.
    f16* q16 = (f16*)d_out;
    f16* k16 = q16 + NQ;
    f16* v16 = k16 + NKV;

    cast_all<<<25440, 256, 0, stream>>>(q_w, k_w, v_w, q, k, v,
                                        qw16, kw16, vw16, q16, k16, v16);

    const float qscale = 0.03608439182435161f;  // 1/sqrt(768)

    proj_all<<<768, 512, 0, stream>>>(q16, qw16, kw16, vw16,
                                      q_b, k_b, v_b, Qp, Kp, VpT, qscale);

    attn_fused<<<512, 256, 0, stream>>>(Qp, Kp, VpT, out);
}